// Round 9
// baseline (2152.153 us; speedup 1.0000x reference)
//
#include <hip/hip_runtime.h>
#include <hip/hip_bf16.h>
#include <stdint.h>
#include <math.h>

#define NUM_FF 7
#define DM 512
#define RD 128
#define VOCABN 128
#define BATCH 128
#define TLEN 1024

typedef unsigned int u32x4 __attribute__((ext_vector_type(4)));

// ---- pack ff, QUAD layout ----
// chunk lq = l*4+j (layer l, quad-col j). word at ffq[lq*2048 + t*4 + k]:
//   bit i = ff[l][ 32*(4*(t&3)+k) + i ][ (t&~3)+j ] > 0
// i.e. thread t's b128 for (l,j) = state-words 4*(t&3)..+3 of column (t&~3)+j.
__global__ void pack_ff_kernel(const float* __restrict__ ff, uint32_t* __restrict__ ffq) {
    int o = blockIdx.x * blockDim.x + threadIdx.x;
    if (o >= NUM_FF * 16 * DM) return;
    int k = o & 3;
    int t = (o >> 2) & (DM - 1);
    int lq = o >> 11;
    int l = lq >> 2, j = lq & 3;
    int col = (t & ~3) + j;
    int wi = 4 * (t & 3) + k;
    const float* base = ff + (size_t)l * DM * DM + (size_t)(wi * 32) * DM + col;
    uint32_t w = 0;
#pragma unroll
    for (int i = 0; i < 32; ++i)
        w |= (base[(size_t)i * DM] > 0.0f ? 1u : 0u) << i;
    ffq[o] = w;
}

// ---- integer thresholds: bit = (512-2a >= th)  <=>  a <= floor((512-th)/2) ----
__global__ void pack_thresh_kernel(const float* __restrict__ th, int* __restrict__ it) {
    int idx = blockIdx.x * blockDim.x + threadIdx.x;
    if (idx < NUM_FF * DM)
        it[idx] = (int)floor((512.0 - (double)th[idx]) * 0.5);
}

// ---- pack embed/head/initial (512 threads, 1 block) ----
__global__ void pack_small_kernel(const float* __restrict__ embed,
                                  const float* __restrict__ head,
                                  const float* __restrict__ initial,
                                  uint32_t* __restrict__ embp,
                                  uint32_t* __restrict__ headp,
                                  uint32_t* __restrict__ initp) {
    int idx = threadIdx.x; // 512
    {   int v = idx >> 2, k = idx & 3;
        uint32_t w = 0;
#pragma unroll
        for (int i = 0; i < 32; ++i)
            w |= (embed[v * RD + k * 32 + i] > 0.0f ? 1u : 0u) << i;
        embp[idx] = w;
    }
    {   int k = idx >> 7, v = idx & 127;
        uint32_t w = 0;
#pragma unroll
        for (int i = 0; i < 32; ++i)
            w |= (head[(k * 32 + i) * VOCABN + v] > 0.0f ? 1u : 0u) << i;
        headp[idx] = w;
    }
    if (idx < 16) {
        uint32_t w = 0;
#pragma unroll
        for (int i = 0; i < 32; ++i)
            w |= (initial[idx * 32 + i] > 0.0f ? 1u : 0u) << i;
        initp[idx] = w;
    }
}

// quad butterfly sum via DPP (VALU pipe, no LDS): after this every lane in a
// quad holds the 4-lane sum.
__device__ __forceinline__ int dppadd(int v) {
    v += __builtin_amdgcn_update_dpp(0, v, 0xB1, 0xF, 0xF, true); // quad_perm [1,0,3,2]
    v += __builtin_amdgcn_update_dpp(0, v, 0x4E, 0xF, 0xF, true); // quad_perm [2,3,0,1]
    return v;
}

// LDS-visibility barrier WITHOUT draining vmcnt
#define SYNCB asm volatile("s_waitcnt lgkmcnt(0)\n\ts_barrier" ::: "memory")

// AGPR pin/read
#define AW(D, S) asm volatile("v_accvgpr_write_b32 %0, %1" : "=a"(D) : "v"(S))
#define AR(S) __extension__({ uint32_t r_; \
        asm volatile("v_accvgpr_read_b32 %0, %1" : "=v"(r_) : "a"(S)); r_; })

// ---- main persistent RNN kernel: 1 workgroup (512 thr, 8 waves) per chain ----
// Bottleneck model (r8 counters): per-CU LDS pipe throughput (~12cyc/b128).
// Old scheme: 64 b128/layer (weights+state broadcast) ~768 cyc. New scheme:
// all weights in registers (48 VGPR + 64 AGPR), state quad-distributed
// (1 b128/wave) + DPP quad reduction -> ~9 LDS ops/layer.
__attribute__((amdgpu_flat_work_group_size(512, 512), amdgpu_waves_per_eu(2, 2)))
__global__ void brnn_kernel(const int* __restrict__ tokens,
                            const uint32_t* __restrict__ ffq,
                            const int* __restrict__ ithr,
                            const uint32_t* __restrict__ embp,
                            const uint32_t* __restrict__ headp,
                            const uint32_t* __restrict__ initp,
                            float* __restrict__ out) {
    const int b = blockIdx.x;
    const int tid = threadIdx.x;      // own output column
    const int wv = tid >> 6;
    const int lane = tid & 63;
    const int lq4 = lane & 3;         // position in quad

    __shared__ uint4 xq0[4], xq1[4];  // double-buffered 512-bit state
    __shared__ uint4 hx4;             // layer-6 read-slice words for head
    __shared__ uint32_t emb_lds[DM];
    __shared__ int tok_lds[TLEN + 2];

    // ---- layers 0-3 weights -> 64 AGPRs (A{L}_{j}{k}) ----
    uint32_t A0_00,A0_01,A0_02,A0_03,A0_10,A0_11,A0_12,A0_13,
             A0_20,A0_21,A0_22,A0_23,A0_30,A0_31,A0_32,A0_33;
    uint32_t A1_00,A1_01,A1_02,A1_03,A1_10,A1_11,A1_12,A1_13,
             A1_20,A1_21,A1_22,A1_23,A1_30,A1_31,A1_32,A1_33;
    uint32_t A2_00,A2_01,A2_02,A2_03,A2_10,A2_11,A2_12,A2_13,
             A2_20,A2_21,A2_22,A2_23,A2_30,A2_31,A2_32,A2_33;
    uint32_t A3_00,A3_01,A3_02,A3_03,A3_10,A3_11,A3_12,A3_13,
             A3_20,A3_21,A3_22,A3_23,A3_30,A3_31,A3_32,A3_33;

#define WLOAD(V, L, Q) asm volatile("global_load_dwordx4 %0, %1, off" \
        : "=v"(V) : "v"(ffq + ((L) * 4 + (Q)) * (DM * 4) + tid * 4))

#define AGLOAD(L) do { u32x4 t0_, t1_, t2_, t3_;                               \
        WLOAD(t0_, L, 0); WLOAD(t1_, L, 1); WLOAD(t2_, L, 2); WLOAD(t3_, L, 3);\
        asm volatile("s_waitcnt vmcnt(0)" ::: "memory");                       \
        AW(A##L##_00, t0_[0]); AW(A##L##_01, t0_[1]);                          \
        AW(A##L##_02, t0_[2]); AW(A##L##_03, t0_[3]);                          \
        AW(A##L##_10, t1_[0]); AW(A##L##_11, t1_[1]);                          \
        AW(A##L##_12, t1_[2]); AW(A##L##_13, t1_[3]);                          \
        AW(A##L##_20, t2_[0]); AW(A##L##_21, t2_[1]);                          \
        AW(A##L##_22, t2_[2]); AW(A##L##_23, t2_[3]);                          \
        AW(A##L##_30, t3_[0]); AW(A##L##_31, t3_[1]);                          \
        AW(A##L##_32, t3_[2]); AW(A##L##_33, t3_[3]);                          \
    } while (0)

    AGLOAD(0); AGLOAD(1); AGLOAD(2); AGLOAD(3);

    // ---- layers 4-6 weights -> 48 VGPRs (r8-proven pin) ----
    u32x4 W40, W41, W42, W43, W50, W51, W52, W53, W60, W61, W62, W63;
    WLOAD(W40, 4, 0); WLOAD(W41, 4, 1); WLOAD(W42, 4, 2); WLOAD(W43, 4, 3);
    WLOAD(W50, 5, 0); WLOAD(W51, 5, 1); WLOAD(W52, 5, 2); WLOAD(W53, 5, 3);
    WLOAD(W60, 6, 0); WLOAD(W61, 6, 1); WLOAD(W62, 6, 2); WLOAD(W63, 6, 3);
#undef WLOAD
    asm volatile("s_waitcnt vmcnt(0)" ::: "memory");

    const int it0 = ithr[0 * DM + tid];
    const int it1 = ithr[1 * DM + tid];
    const int it2 = ithr[2 * DM + tid];
    const int it3 = ithr[3 * DM + tid];
    const int it4 = ithr[4 * DM + tid];
    const int it5 = ithr[5 * DM + tid];
    const int it6 = ithr[6 * DM + tid];

    const int hvv = (wv << 4) | (lane & 15);
    const uint32_t h0 = headp[0 * VOCABN + hvv];
    const uint32_t h1 = headp[1 * VOCABN + hvv];
    const uint32_t h2 = headp[2 * VOCABN + hvv];
    const uint32_t h3 = headp[3 * VOCABN + hvv];

    emb_lds[tid] = embp[tid];
    tok_lds[tid] = tokens[b * TLEN + tid];
    tok_lds[tid + 512] = tokens[b * TLEN + tid + 512];
    if (tid == 0) { tok_lds[TLEN] = 0; tok_lds[TLEN + 1] = 0; }
    if (tid < 16) ((uint32_t*)xq0)[tid] = initp[tid];
    __syncthreads();
    if (tid < 4) ((uint32_t*)xq0)[12 + tid] = emb_lds[tok_lds[0] * 4 + tid];
    __syncthreads();

    float* outb = out + (size_t)b * TLEN * VOCABN;

    // VGPR-weight layer: state = 1 b128/lane (own 4 words), 4 quad-col partial
    // dots, DPP quad reduce, select own col, ballot, lane0 writes 2 words.
#define QDOTV(a, xs, W) \
        int a = __popc(xs.x ^ W[0]); a += __popc(xs.y ^ W[1]); \
        a += __popc(xs.z ^ W[2]); a += __popc(xs.w ^ W[3])

#define QLAYER_V(L, SRCQ, DSTQ) do {                                           \
        uint4 xs = (SRCQ)[lq4];                                                \
        QDOTV(a0, xs, W##L##0); QDOTV(a1, xs, W##L##1);                        \
        QDOTV(a2, xs, W##L##2); QDOTV(a3, xs, W##L##3);                        \
        a0 = dppadd(a0); a1 = dppadd(a1); a2 = dppadd(a2); a3 = dppadd(a3);    \
        int acc = lq4 == 0 ? a0 : (lq4 == 1 ? a1 : (lq4 == 2 ? a2 : a3));      \
        unsigned long long m = __ballot(acc <= it##L);                         \
        if (lane == 0)                                                         \
            ((uint2*)(DSTQ))[wv] = make_uint2((uint32_t)m, (uint32_t)(m >> 32)); \
        SYNCB;                                                                 \
    } while (0)

#define QDOTA(a, xs, L, J) \
        int a = __popc(xs.x ^ AR(A##L##_##J##0)); \
        a += __popc(xs.y ^ AR(A##L##_##J##1)); \
        a += __popc(xs.z ^ AR(A##L##_##J##2)); \
        a += __popc(xs.w ^ AR(A##L##_##J##3))

#define QLAYER_A(L, SRCQ, DSTQ) do {                                           \
        uint4 xs = (SRCQ)[lq4];                                                \
        QDOTA(a0, xs, L, 0); QDOTA(a1, xs, L, 1);                              \
        QDOTA(a2, xs, L, 2); QDOTA(a3, xs, L, 3);                              \
        a0 = dppadd(a0); a1 = dppadd(a1); a2 = dppadd(a2); a3 = dppadd(a3);    \
        int acc = lq4 == 0 ? a0 : (lq4 == 1 ? a1 : (lq4 == 2 ? a2 : a3));      \
        unsigned long long m = __ballot(acc <= it##L);                         \
        if (lane == 0)                                                         \
            ((uint2*)(DSTQ))[wv] = make_uint2((uint32_t)m, (uint32_t)(m >> 32)); \
        SYNCB;                                                                 \
    } while (0)

#define QLAYERF(SRCQ, DSTQ) do {                                               \
        uint4 xs = (SRCQ)[lq4];                                                \
        QDOTV(a0, xs, W60); QDOTV(a1, xs, W61);                                \
        QDOTV(a2, xs, W62); QDOTV(a3, xs, W63);                                \
        a0 = dppadd(a0); a1 = dppadd(a1); a2 = dppadd(a2); a3 = dppadd(a3);    \
        int acc = lq4 == 0 ? a0 : (lq4 == 1 ? a1 : (lq4 == 2 ? a2 : a3));      \
        unsigned long long m = __ballot(acc <= it6);                           \
        if (lane == 0) {                                                       \
            uint2 v_ = make_uint2((uint32_t)m, (uint32_t)(m >> 32));           \
            if (wv < 6) ((uint2*)(DSTQ))[wv] = v_;                             \
            else ((uint2*)&hx4)[wv - 6] = v_;                                  \
        }                                                                      \
        if (wv == 7 && lane < 4) ((uint32_t*)(DSTQ))[12 + lane] = embw;        \
        SYNCB;                                                                 \
    } while (0)

#define STEP(AQ, BQ, T) do {                                                   \
        uint32_t embw = 0;                                                     \
        if (wv == 7) embw = emb_lds[tok_lds[(T) + 1] * 4 + (lane & 3)];        \
        QLAYER_A(0, AQ, BQ);                                                   \
        QLAYER_A(1, BQ, AQ);                                                   \
        QLAYER_A(2, AQ, BQ);                                                   \
        QLAYER_A(3, BQ, AQ);                                                   \
        QLAYER_V(4, AQ, BQ);                                                   \
        QLAYER_V(5, BQ, AQ);                                                   \
        QLAYERF(AQ, BQ);                                                       \
        uint4 hv_ = hx4;                                                       \
        if (lane < 16) {                                                       \
            int hc = __popc(hv_.x ^ h0) + __popc(hv_.y ^ h1) +                 \
                     __popc(hv_.z ^ h2) + __popc(hv_.w ^ h3);                  \
            outb[(T) * VOCABN + hvv] = (float)(RD - 2 * hc);                   \
        }                                                                      \
    } while (0)

    for (int t = 0; t < TLEN; t += 2) {
        STEP(xq0, xq1, t);
        STEP(xq1, xq0, t + 1);
    }
}

extern "C" void kernel_launch(void* const* d_in, const int* in_sizes, int n_in,
                              void* d_out, int out_size, void* d_ws, size_t ws_size,
                              hipStream_t stream) {
    const int* tokens = (const int*)d_in[0];
    const float* initial = (const float*)d_in[1];
    const float* embed = (const float*)d_in[2];
    const float* ff = (const float*)d_in[3];
    const float* ff_thresh = (const float*)d_in[4];
    const float* head = (const float*)d_in[5];
    float* out = (float*)d_out;

    uint32_t* ffq = (uint32_t*)d_ws;              // 7*16*512 words, quad layout
    uint32_t* embp = ffq + NUM_FF * 16 * DM;      // 512 words
    uint32_t* headp = embp + 512;                 // 512 words
    uint32_t* initp = headp + 512;                // 16 words
    int* ithr = (int*)(initp + 16);               // 7*512 ints

    pack_ff_kernel<<<(NUM_FF * 16 * DM + 255) / 256, 256, 0, stream>>>(ff, ffq);
    pack_thresh_kernel<<<(NUM_FF * DM + 255) / 256, 256, 0, stream>>>(ff_thresh, ithr);
    pack_small_kernel<<<1, 512, 0, stream>>>(embed, head, initial, embp, headp, initp);
    brnn_kernel<<<BATCH, 512, 0, stream>>>(tokens, ffq, ithr, embp, headp, initp, out);
}